// Round 5
// baseline (682.432 us; speedup 1.0000x reference)
//
#include <hip/hip_runtime.h>

// CosformerAttention on MI355X (gfx950). Inputs fp32, OUTPUT fp32.
// B=8, E=768, L=48*48=2304, heads=12, d=64, n=B*h=96, M=L*B=18432.
//
// Round-5: r2/r4 bit-identical absmax across MFMA vs VALU GEMMs proved the
// compute fabric correct; the bug was writing bf16 into the fp32 d_out
// (absmax 4.05 = sqrt(2)*max|ref| signature + zero second half). Fix: MODE-1
// epilogue writes float. MFMA GEMM restored (validated by the bisection).

#define L_SEQ 2304
#define BATCH 8
#define EDIM 768
#define NHEAD 12
#define DHEAD 64
#define MROWS (L_SEQ * BATCH)  // 18432

typedef __attribute__((ext_vector_type(8))) short bf16x8_t;   // 8 bf16 = 4 VGPRs
typedef __attribute__((ext_vector_type(4))) float f32x4_t;

__device__ __forceinline__ float b2f(unsigned short u) {
  union { unsigned int i; float f; } x; x.i = ((unsigned int)u) << 16; return x.f;
}
__device__ __forceinline__ unsigned short f2b(float f) {
  union { float f; unsigned int i; } x; x.f = f;
  unsigned int r = x.i + 0x7FFFu + ((x.i >> 16) & 1u);  // RNE
  return (unsigned short)(r >> 16);
}

// ---------------------------------------------------------------------------
// Kernel 0: convert 4 fp32 weight matrices (768x768) to bf16.
// grid (576, 4), block 256; each thread converts 4 elements (float4 load).
__global__ __launch_bounds__(256) void conv_w(
    const float* __restrict__ W0, const float* __restrict__ W1,
    const float* __restrict__ W2, const float* __restrict__ W3,
    unsigned short* __restrict__ dst) {
  const float* W = (blockIdx.y == 0) ? W0 : (blockIdx.y == 1) ? W1
                 : (blockIdx.y == 2) ? W2 : W3;
  unsigned short* d = dst + (size_t)blockIdx.y * EDIM * EDIM;
  int idx = blockIdx.x * 256 + threadIdx.x;  // [0, 147456)
  float4 v = *(const float4*)(W + (size_t)idx * 4);
  ushort4 o;
  o.x = f2b(v.x); o.y = f2b(v.y); o.z = f2b(v.z); o.w = f2b(v.w);
  *(ushort4*)(d + (size_t)idx * 4) = o;
}

// ---------------------------------------------------------------------------
// Kernel 1: transpose query (B, E, L) fp32 -> xT (B*L, E) bf16.
// grid: (E/64=12, L/64=36, B=8), block 256
__global__ __launch_bounds__(256) void transpose_q(
    const float* __restrict__ q, unsigned short* __restrict__ xT) {
  __shared__ float tile[64][65];  // +1 pad
  int b = blockIdx.z;
  int e0 = blockIdx.x * 64;
  int l0 = blockIdx.y * 64;
  int t = threadIdx.x;
  int li = t & 63, er = t >> 6;
#pragma unroll
  for (int p = 0; p < 16; p++) {
    int eo = er + p * 4;
    tile[eo][li] = q[((size_t)b * EDIM + (e0 + eo)) * L_SEQ + (l0 + li)];
  }
  __syncthreads();
  int ei = t & 63, lr = t >> 6;
#pragma unroll
  for (int p = 0; p < 16; p++) {
    int lo = lr + p * 4;
    xT[((size_t)b * L_SEQ + (l0 + lo)) * EDIM + (e0 + ei)] = f2b(tile[ei][lo]);
  }
}

// ---------------------------------------------------------------------------
// Kernel 2/5: C = A @ W^T (+bias, opt relu), A (M x 768) bf16 K-contig,
// W (768 x 768) bf16 K-contig, bias fp32. 128x128 tile, BK=32, 4 waves,
// 4x4 MFMA (16x16x32 bf16) acc/wave.
// MODE 0: qkv projections (blockIdx.z picks W/bias/dst; relu for z<2);
//         epilogue writes bf16 head layout dst[n=(b*12+o/64)][l][o%64].
// MODE 1: final projection; writes FP32 dstf[m*768+o] (= (l*B+b)*E+e flat).
template <int MODE>
__global__ __launch_bounds__(256) void gemm_bt(
    const unsigned short* __restrict__ A,
    const unsigned short* __restrict__ Wall,
    const float* __restrict__ bias0, const float* __restrict__ bias1,
    const float* __restrict__ bias2,
    unsigned short* __restrict__ dst0, unsigned short* __restrict__ dst1,
    unsigned short* __restrict__ dst2,
    float* __restrict__ dstf) {
  constexpr int BM = 128, BN = 128, BK = 32, K = EDIM;
  __shared__ __align__(16) unsigned short As[BM * BK];
  __shared__ __align__(16) unsigned short Bs[BN * BK];

  const unsigned short* W;
  const float* bias;
  unsigned short* dst;
  bool do_relu;
  if (MODE == 0) {
    int z = blockIdx.z;
    W    = Wall + (size_t)z * EDIM * EDIM;
    bias = (z == 0) ? bias0 : (z == 1) ? bias1 : bias2;
    dst  = (z == 0) ? dst0 : (z == 1) ? dst1 : dst2;
    do_relu = (z < 2);
  } else {
    W = Wall; bias = bias0; dst = dst0; do_relu = false;
  }

  int t = threadIdx.x;
  int lane = t & 63;
  int wave = t >> 6;
  int wr = (wave & 1) * 64;   // wave's 64x64 quadrant
  int wc = (wave >> 1) * 64;
  int row0 = blockIdx.x * BM;
  int col0 = blockIdx.y * BN;
  int mrow = lane & 15, quad = lane >> 4;

  f32x4_t acc[4][4] = {};

  for (int k0 = 0; k0 < K; k0 += BK) {
    // stage A/B tiles (128x32 bf16 = 8KB each); chunk c -> row c/4, k (c%4)*8
#pragma unroll
    for (int i = 0; i < 2; i++) {
      int c = t + i * 256;
      int r = c >> 2;
      int kk = (c & 3) * 8;
      *(uint4*)(As + r * BK + kk) = *(const uint4*)(A + (size_t)(row0 + r) * K + (k0 + kk));
      *(uint4*)(Bs + r * BK + kk) = *(const uint4*)(W + (size_t)(col0 + r) * K + (k0 + kk));
    }
    __syncthreads();
    // fragments: A[m=lane&15][k=quad*8+j], B[n=lane&15][k=quad*8+j]
    bf16x8_t af[4], bfr[4];
#pragma unroll
    for (int i = 0; i < 4; i++) {
      af[i]  = *(const bf16x8_t*)(As + (wr + i * 16 + mrow) * BK + quad * 8);
      bfr[i] = *(const bf16x8_t*)(Bs + (wc + i * 16 + mrow) * BK + quad * 8);
    }
#pragma unroll
    for (int ti = 0; ti < 4; ti++)
#pragma unroll
      for (int tj = 0; tj < 4; tj++)
        acc[ti][tj] = __builtin_amdgcn_mfma_f32_16x16x32_bf16(af[ti], bfr[tj], acc[ti][tj], 0, 0, 0);
    __syncthreads();
  }

  // epilogue: D col = lane&15, row = quad*4 + r  (m89-verified layout)
  int bb = row0 / L_SEQ;  // tile lies in one b (2304 % 128 == 0)
#pragma unroll
  for (int ti = 0; ti < 4; ti++) {
#pragma unroll
    for (int tj = 0; tj < 4; tj++) {
      int gc = col0 + wc + tj * 16 + (lane & 15);
      float bv = bias[gc];
#pragma unroll
      for (int r = 0; r < 4; r++) {
        int gr = row0 + wr + ti * 16 + quad * 4 + r;
        float v = acc[ti][tj][r] + bv;
        if (MODE == 0) {
          if (do_relu) v = fmaxf(v, 0.0f);
          int ll = gr - bb * L_SEQ;
          int n = bb * NHEAD + (gc >> 6);
          dst[((size_t)n * L_SEQ + ll) * DHEAD + (gc & 63)] = f2b(v);
        } else {
          dstf[(size_t)gr * EDIM + gc] = v;  // FP32 output
        }
      }
    }
  }
}

// ---------------------------------------------------------------------------
// Kernel 3: kv[n][j][m] = sum_l k_[n][l][j] * v[n][l][m],  ksum[n][j] = sum_l k_
// k_ = [k*sin ; k*cos] built on the fly. grid (96, 8), block 256.
__global__ __launch_bounds__(256) void kv_reduce(
    const unsigned short* __restrict__ kbuf, const unsigned short* __restrict__ vbuf,
    float* __restrict__ kv, float* __restrict__ ksum) {
  constexpr int TL = 16, CHUNK = L_SEQ / 8;  // 288
  __shared__ float ks[TL][128];
  __shared__ float vs[TL][64];
  int n = blockIdx.x;
  int lbase = blockIdx.y * CHUNK;
  int t = threadIdx.x;
  int jg = t >> 4, mg = t & 15;
  float acc[8][4] = {};
  float ksacc[8] = {};
  for (int c = 0; c < CHUNK; c += TL) {
#pragma unroll
    for (int p = 0; p < 4; p++) {
      int li = (t >> 6) * 4 + p;
      int j = t & 63;
      int l = lbase + c + li;
      float sv, cv;
      sincosf(1.5707963267948966f * (float)(l + 1) / 2304.0f, &sv, &cv);
      float kval = b2f(kbuf[((size_t)n * L_SEQ + l) * DHEAD + j]);
      ks[li][j] = kval * sv;
      ks[li][j + 64] = kval * cv;
      vs[li][j] = b2f(vbuf[((size_t)n * L_SEQ + l) * DHEAD + j]);
    }
    __syncthreads();
#pragma unroll 4
    for (int l = 0; l < TL; l++) {
      float kj[8], vm[4];
#pragma unroll
      for (int i = 0; i < 8; i++) kj[i] = ks[l][jg + 16 * i];
#pragma unroll
      for (int i = 0; i < 4; i++) vm[i] = vs[l][mg + 16 * i];
#pragma unroll
      for (int i = 0; i < 8; i++)
#pragma unroll
        for (int i2 = 0; i2 < 4; i2++) acc[i][i2] += kj[i] * vm[i2];
      if (mg == 0) {
#pragma unroll
        for (int i = 0; i < 8; i++) ksacc[i] += kj[i];
      }
    }
    __syncthreads();
  }
#pragma unroll
  for (int i = 0; i < 8; i++) {
    int j = jg + 16 * i;
#pragma unroll
    for (int i2 = 0; i2 < 4; i2++)
      atomicAdd(&kv[((size_t)n * 128 + j) * 64 + (mg + 16 * i2)], acc[i][i2]);
    if (mg == 0) atomicAdd(&ksum[n * 128 + j], ksacc[i]);
  }
}

// ---------------------------------------------------------------------------
// Kernel 4: out[n][l][m] = z * (sin*(q.kv0[:,m]) + cos*(q.kv1[:,m])), fused
// residual + relayout into attn[(l*B+b)*E + hd*64+m] (bf16).
__global__ __launch_bounds__(256) void attn_out(
    const unsigned short* __restrict__ qbuf, const float* __restrict__ kv,
    const float* __restrict__ ksum, const unsigned short* __restrict__ xT,
    unsigned short* __restrict__ attn) {
  constexpr int CHUNK = L_SEQ / 12;  // 192
  __shared__ float kvb[128 * 64];    // 32 KB, whole-head kv
  int n = blockIdx.x;
  int lbase = blockIdx.y * CHUNK;
  int t = threadIdx.x;
#pragma unroll
  for (int i = 0; i < 32; i++) kvb[t + 256 * i] = kv[(size_t)n * 8192 + t + 256 * i];
  int lane = t & 63, lg = t >> 6;
  float kss = ksum[n * 128 + lane];
  float ksc = ksum[n * 128 + 64 + lane];
  int b = n / NHEAD, hd = n % NHEAD;
  __syncthreads();
  for (int c = 0; c < CHUNK; c += 4) {
    int l = lbase + c + lg;  // wave-uniform
    float qv_own = b2f(qbuf[((size_t)n * L_SEQ + l) * DHEAD + lane]);
    float sv, cv;
    sincosf(1.5707963267948966f * (float)(l + 1) / 2304.0f, &sv, &cv);
    float p = qv_own * (sv * kss + cv * ksc);
#pragma unroll
    for (int o = 32; o > 0; o >>= 1) p += __shfl_xor(p, o);
    float z = 1.0f / fmaxf(p, 1e-6f);
    float acc0 = 0.f, acc1 = 0.f;
#pragma unroll 8
    for (int j0 = 0; j0 < 64; j0++) {
      float qv = __shfl(qv_own, j0);
      acc0 += qv * kvb[j0 * 64 + lane];
      acc1 += qv * kvb[(j0 + 64) * 64 + lane];
    }
    float ov = z * (sv * acc0 + cv * acc1);
    float xv = b2f(xT[((size_t)b * L_SEQ + l) * EDIM + hd * DHEAD + lane]);
    attn[((size_t)l * BATCH + b) * EDIM + hd * DHEAD + lane] = f2b(xv + ov);
  }
}

// ---------------------------------------------------------------------------
extern "C" void kernel_launch(void* const* d_in, const int* in_sizes, int n_in,
                              void* d_out, int out_size, void* d_ws, size_t ws_size,
                              hipStream_t stream) {
  const float* query = (const float*)d_in[0];
  const float* Wq = (const float*)d_in[1];
  const float* bq = (const float*)d_in[2];
  const float* Wk = (const float*)d_in[3];
  const float* bk = (const float*)d_in[4];
  const float* Wv = (const float*)d_in[5];
  const float* bv = (const float*)d_in[6];
  const float* Wo = (const float*)d_in[7];
  const float* bo = (const float*)d_in[8];
  float* out = (float*)d_out;  // fp32 output, 18432*768 elements

  // xT (bf16, 28.3 MB) staged inside d_out (56.6 MB fp32); xT's last reader
  // (attn_out) completes before the final GEMM overwrites d_out.
  unsigned short* xT = (unsigned short*)d_out;

  char* ws = (char*)d_ws;
  const size_t SZ = (size_t)MROWS * EDIM * 2;  // 28,311,552
  unsigned short* qbuf = (unsigned short*)(ws);
  unsigned short* kbuf = (unsigned short*)(ws + SZ);
  unsigned short* vbuf = (unsigned short*)(ws + 2 * SZ);
  unsigned short* attn = kbuf;  // kbuf dead after kv_reduce
  float* kv   = (float*)(ws + 3 * SZ);                    // 3,145,728 B
  float* ksum = (float*)(ws + 3 * SZ + 3145728);          // 49,152 B
  unsigned short* wbf = (unsigned short*)(ws + 3 * SZ + 3145728 + 49152);
  // total ws: 92,848,128 B

  conv_w<<<dim3(576, 4), 256, 0, stream>>>(Wq, Wk, Wv, Wo, wbf);

  transpose_q<<<dim3(12, 36, 8), 256, 0, stream>>>(query, xT);

  gemm_bt<0><<<dim3(MROWS / 128, EDIM / 128, 3), 256, 0, stream>>>(
      xT, wbf, bq, bk, bv, qbuf, kbuf, vbuf, nullptr);

  hipMemsetAsync(ws + 3 * SZ, 0, 3145728 + 49152, stream);

  kv_reduce<<<dim3(96, 8), 256, 0, stream>>>(kbuf, vbuf, kv, ksum);

  attn_out<<<dim3(96, 12), 256, 0, stream>>>(qbuf, kv, ksum, xT, attn);

  gemm_bt<1><<<dim3(MROWS / 128, EDIM / 128, 1), 256, 0, stream>>>(
      attn, wbf + 3 * (size_t)EDIM * EDIM, bo, nullptr, nullptr,
      nullptr, nullptr, nullptr, out);
}

// Round 6
// 387.075 us; speedup vs baseline: 1.7631x; 1.7631x over previous
//
#include <hip/hip_runtime.h>

// CosformerAttention on MI355X (gfx950). Inputs fp32, OUTPUT fp32.
// B=8, E=768, L=48*48=2304, heads=12, d=64, n=B*h=96, M=L*B=18432.
//
// Round-6: r5 passed at 682 us with attn_out = 330 us (MfmaUtil 0, LDS-bound).
// (1) attn_out rewritten as MFMA: C = sin*(q@kv0) + cos*(q@kv1), two K=64
//     bf16 GEMMs per head; denom from staged A-tile; fused residual+relayout.
// (2) gemm_bt staging switched to global_load_lds width=16 (m97 ladder).

#define L_SEQ 2304
#define BATCH 8
#define EDIM 768
#define NHEAD 12
#define DHEAD 64
#define MROWS (L_SEQ * BATCH)  // 18432

typedef __attribute__((ext_vector_type(8))) short bf16x8_t;   // 8 bf16 = 4 VGPRs
typedef __attribute__((ext_vector_type(4))) float f32x4_t;

__device__ __forceinline__ float b2f(unsigned short u) {
  union { unsigned int i; float f; } x; x.i = ((unsigned int)u) << 16; return x.f;
}
__device__ __forceinline__ unsigned short f2b(float f) {
  union { float f; unsigned int i; } x; x.f = f;
  unsigned int r = x.i + 0x7FFFu + ((x.i >> 16) & 1u);  // RNE
  return (unsigned short)(r >> 16);
}

// async 16B global->LDS (gfx950; wave-uniform base + lane*16 dest contract —
// our LDS offsets are linear in thread id, satisfying it)
#define GLOAD_LDS16(g, l)                                                     \
  __builtin_amdgcn_global_load_lds(                                           \
      (const __attribute__((address_space(1))) unsigned int*)(g),             \
      (__attribute__((address_space(3))) unsigned int*)(l), 16, 0, 0)

// ---------------------------------------------------------------------------
// Kernel 0: convert 4 fp32 weight matrices (768x768) to bf16.
__global__ __launch_bounds__(256) void conv_w(
    const float* __restrict__ W0, const float* __restrict__ W1,
    const float* __restrict__ W2, const float* __restrict__ W3,
    unsigned short* __restrict__ dst) {
  const float* W = (blockIdx.y == 0) ? W0 : (blockIdx.y == 1) ? W1
                 : (blockIdx.y == 2) ? W2 : W3;
  unsigned short* d = dst + (size_t)blockIdx.y * EDIM * EDIM;
  int idx = blockIdx.x * 256 + threadIdx.x;  // [0, 147456)
  float4 v = *(const float4*)(W + (size_t)idx * 4);
  ushort4 o;
  o.x = f2b(v.x); o.y = f2b(v.y); o.z = f2b(v.z); o.w = f2b(v.w);
  *(ushort4*)(d + (size_t)idx * 4) = o;
}

// ---------------------------------------------------------------------------
// Kernel 1: transpose query (B, E, L) fp32 -> xT (B*L, E) bf16.
__global__ __launch_bounds__(256) void transpose_q(
    const float* __restrict__ q, unsigned short* __restrict__ xT) {
  __shared__ float tile[64][65];
  int b = blockIdx.z;
  int e0 = blockIdx.x * 64;
  int l0 = blockIdx.y * 64;
  int t = threadIdx.x;
  int li = t & 63, er = t >> 6;
#pragma unroll
  for (int p = 0; p < 16; p++) {
    int eo = er + p * 4;
    tile[eo][li] = q[((size_t)b * EDIM + (e0 + eo)) * L_SEQ + (l0 + li)];
  }
  __syncthreads();
  int ei = t & 63, lr = t >> 6;
#pragma unroll
  for (int p = 0; p < 16; p++) {
    int lo = lr + p * 4;
    xT[((size_t)b * L_SEQ + (l0 + lo)) * EDIM + (e0 + ei)] = f2b(tile[ei][lo]);
  }
}

// ---------------------------------------------------------------------------
// Kernel 2/5: C = A @ W^T (+bias, opt relu). 128x128 tile, BK=32, 4 waves,
// 4x4 MFMA (16x16x32 bf16) acc/wave. Staging via global_load_lds width=16.
template <int MODE>
__global__ __launch_bounds__(256) void gemm_bt(
    const unsigned short* __restrict__ A,
    const unsigned short* __restrict__ Wall,
    const float* __restrict__ bias0, const float* __restrict__ bias1,
    const float* __restrict__ bias2,
    unsigned short* __restrict__ dst0, unsigned short* __restrict__ dst1,
    unsigned short* __restrict__ dst2,
    float* __restrict__ dstf) {
  constexpr int BM = 128, BN = 128, BK = 32, K = EDIM;
  __shared__ __align__(16) unsigned short As[BM * BK];
  __shared__ __align__(16) unsigned short Bs[BN * BK];

  const unsigned short* W;
  const float* bias;
  unsigned short* dst;
  bool do_relu;
  if (MODE == 0) {
    int z = blockIdx.z;
    W    = Wall + (size_t)z * EDIM * EDIM;
    bias = (z == 0) ? bias0 : (z == 1) ? bias1 : bias2;
    dst  = (z == 0) ? dst0 : (z == 1) ? dst1 : dst2;
    do_relu = (z < 2);
  } else {
    W = Wall; bias = bias0; dst = dst0; do_relu = false;
  }

  int t = threadIdx.x;
  int lane = t & 63;
  int wave = t >> 6;
  int wr = (wave & 1) * 64;
  int wc = (wave >> 1) * 64;
  int row0 = blockIdx.x * BM;
  int col0 = blockIdx.y * BN;
  int mrow = lane & 15, quad = lane >> 4;

  f32x4_t acc[4][4] = {};

  for (int k0 = 0; k0 < K; k0 += BK) {
    // stage A/B tiles: chunk c -> row c/4, k (c%4)*8; LDS byte offset = c*16
    // (linear in thread id => matches global_load_lds lane*16 placement)
#pragma unroll
    for (int i = 0; i < 2; i++) {
      int c = t + i * 256;
      int r = c >> 2;
      int kk = (c & 3) * 8;
      GLOAD_LDS16(A + (size_t)(row0 + r) * K + (k0 + kk), As + (size_t)c * 8);
      GLOAD_LDS16(W + (size_t)(col0 + r) * K + (k0 + kk), Bs + (size_t)c * 8);
    }
    __syncthreads();
    bf16x8_t af[4], bfr[4];
#pragma unroll
    for (int i = 0; i < 4; i++) {
      af[i]  = *(const bf16x8_t*)(As + (wr + i * 16 + mrow) * BK + quad * 8);
      bfr[i] = *(const bf16x8_t*)(Bs + (wc + i * 16 + mrow) * BK + quad * 8);
    }
#pragma unroll
    for (int ti = 0; ti < 4; ti++)
#pragma unroll
      for (int tj = 0; tj < 4; tj++)
        acc[ti][tj] = __builtin_amdgcn_mfma_f32_16x16x32_bf16(af[ti], bfr[tj], acc[ti][tj], 0, 0, 0);
    __syncthreads();
  }

  // epilogue: D col = lane&15, row = quad*4 + r
  int bb = row0 / L_SEQ;
#pragma unroll
  for (int ti = 0; ti < 4; ti++) {
#pragma unroll
    for (int tj = 0; tj < 4; tj++) {
      int gc = col0 + wc + tj * 16 + (lane & 15);
      float bv = bias[gc];
#pragma unroll
      for (int r = 0; r < 4; r++) {
        int gr = row0 + wr + ti * 16 + quad * 4 + r;
        float v = acc[ti][tj][r] + bv;
        if (MODE == 0) {
          if (do_relu) v = fmaxf(v, 0.0f);
          int ll = gr - bb * L_SEQ;
          int n = bb * NHEAD + (gc >> 6);
          dst[((size_t)n * L_SEQ + ll) * DHEAD + (gc & 63)] = f2b(v);
        } else {
          dstf[(size_t)gr * EDIM + gc] = v;  // FP32 output
        }
      }
    }
  }
}

// ---------------------------------------------------------------------------
// Kernel 3: kv[n][j][m] = sum_l k_[n][l][j] * v[n][l][m],  ksum[n][j] = sum_l k_
__global__ __launch_bounds__(256) void kv_reduce(
    const unsigned short* __restrict__ kbuf, const unsigned short* __restrict__ vbuf,
    float* __restrict__ kv, float* __restrict__ ksum) {
  constexpr int TL = 16, CHUNK = L_SEQ / 8;  // 288
  __shared__ float ks[TL][128];
  __shared__ float vs[TL][64];
  int n = blockIdx.x;
  int lbase = blockIdx.y * CHUNK;
  int t = threadIdx.x;
  int jg = t >> 4, mg = t & 15;
  float acc[8][4] = {};
  float ksacc[8] = {};
  for (int c = 0; c < CHUNK; c += TL) {
#pragma unroll
    for (int p = 0; p < 4; p++) {
      int li = (t >> 6) * 4 + p;
      int j = t & 63;
      int l = lbase + c + li;
      float sv, cv;
      sincosf(1.5707963267948966f * (float)(l + 1) / 2304.0f, &sv, &cv);
      float kval = b2f(kbuf[((size_t)n * L_SEQ + l) * DHEAD + j]);
      ks[li][j] = kval * sv;
      ks[li][j + 64] = kval * cv;
      vs[li][j] = b2f(vbuf[((size_t)n * L_SEQ + l) * DHEAD + j]);
    }
    __syncthreads();
#pragma unroll 4
    for (int l = 0; l < TL; l++) {
      float kj[8], vm[4];
#pragma unroll
      for (int i = 0; i < 8; i++) kj[i] = ks[l][jg + 16 * i];
#pragma unroll
      for (int i = 0; i < 4; i++) vm[i] = vs[l][mg + 16 * i];
#pragma unroll
      for (int i = 0; i < 8; i++)
#pragma unroll
        for (int i2 = 0; i2 < 4; i2++) acc[i][i2] += kj[i] * vm[i2];
      if (mg == 0) {
#pragma unroll
        for (int i = 0; i < 8; i++) ksacc[i] += kj[i];
      }
    }
    __syncthreads();
  }
#pragma unroll
  for (int i = 0; i < 8; i++) {
    int j = jg + 16 * i;
#pragma unroll
    for (int i2 = 0; i2 < 4; i2++)
      atomicAdd(&kv[((size_t)n * 128 + j) * 64 + (mg + 16 * i2)], acc[i][i2]);
    if (mg == 0) atomicAdd(&ksum[n * 128 + j], ksacc[i]);
  }
}

// ---------------------------------------------------------------------------
// Kernel 4 (MFMA): per (L-tile of 128, head n):
//   C0 = q @ kv0, C1 = q @ kv1  (K=64 bf16 MFMA GEMMs)
//   out = zs[row]*C0 + zc[row]*C1, zs=z*sin, zc=z*cos, z=1/max(denom,eps)
//   attn[(l*B+b)*E + hd*64+m] = xT[(b*L+l)*E + hd*64+m] + out   (bf16)
// grid (L/128 = 18, 96), block 256 (4 waves; wave owns 32 rows x 64 cols).
__global__ __launch_bounds__(256) void attn_mfma(
    const unsigned short* __restrict__ qbuf, const float* __restrict__ kv,
    const float* __restrict__ ksum, const unsigned short* __restrict__ xT,
    unsigned short* __restrict__ attn) {
  __shared__ __align__(16) unsigned short As[128 * 72];  // q tile, stride 72
  __shared__ __align__(16) unsigned short Bs[64 * 136];  // kv^T bf16, stride 136
  __shared__ float ks_l[128];
  __shared__ float zs[128], zc[128];
  int l0 = blockIdx.x * 128;
  int n = blockIdx.y;
  int t = threadIdx.x;
  int lane = t & 63, wave = t >> 6;
  int mrow = lane & 15, quad = lane >> 4;
  int b = n / NHEAD, hd = n % NHEAD;

  // stage A: rows l0..+127, 64 bf16 each (thread: row t/2, half (t&1)*32)
  {
    int row = t >> 1, off = (t & 1) * 32;
    const unsigned short* src = qbuf + ((size_t)n * L_SEQ + l0 + row) * DHEAD + off;
    unsigned short* d = As + row * 72 + off;
#pragma unroll
    for (int c = 0; c < 4; c++)
      *(uint4*)(d + c * 8) = *(const uint4*)(src + c * 8);
  }
  // stage B: kv[n][j][m] fp32 -> Bs[m][j] bf16 (transpose+convert, L2-hot)
  {
    int j = t >> 1, mh = (t & 1) * 32;
    const float* src = kv + ((size_t)n * 128 + j) * 64 + mh;
#pragma unroll
    for (int mm = 0; mm < 32; mm++)
      Bs[(mh + mm) * 136 + j] = f2b(src[mm]);
  }
  if (t < 128) ks_l[t] = ksum[n * 128 + t];
  __syncthreads();

  // per-row denominator from staged A-tile
  if (t < 128) {
    float d0 = 0.f, d1 = 0.f;
    const unsigned short* arow = As + t * 72;
#pragma unroll
    for (int j = 0; j < 8; j++) {
      bf16x8_t v = *(const bf16x8_t*)(arow + j * 8);
#pragma unroll
      for (int e = 0; e < 8; e++) {
        float qv = b2f((unsigned short)v[e]);
        d0 += qv * ks_l[j * 8 + e];
        d1 += qv * ks_l[64 + j * 8 + e];
      }
    }
    float sv, cv;
    sincosf(1.5707963267948966f * (float)(l0 + t + 1) / 2304.0f, &sv, &cv);
    float z = 1.0f / fmaxf(sv * d0 + cv * d1, 1e-6f);
    zs[t] = z * sv;
    zc[t] = z * cv;
  }
  __syncthreads();

  int wr = wave * 32;
  f32x4_t acc0[2][4] = {}, acc1[2][4] = {};
#pragma unroll
  for (int ks = 0; ks < 2; ks++) {
    bf16x8_t af[2];
#pragma unroll
    for (int ti = 0; ti < 2; ti++)
      af[ti] = *(const bf16x8_t*)(As + (wr + ti * 16 + mrow) * 72 + ks * 32 + quad * 8);
#pragma unroll
    for (int tj = 0; tj < 4; tj++) {
      bf16x8_t b0 = *(const bf16x8_t*)(Bs + (tj * 16 + mrow) * 136 + ks * 32 + quad * 8);
      bf16x8_t b1 = *(const bf16x8_t*)(Bs + (tj * 16 + mrow) * 136 + 64 + ks * 32 + quad * 8);
#pragma unroll
      for (int ti = 0; ti < 2; ti++) {
        acc0[ti][tj] = __builtin_amdgcn_mfma_f32_16x16x32_bf16(af[ti], b0, acc0[ti][tj], 0, 0, 0);
        acc1[ti][tj] = __builtin_amdgcn_mfma_f32_16x16x32_bf16(af[ti], b1, acc1[ti][tj], 0, 0, 0);
      }
    }
  }

  // epilogue: D col = lane&15, row = quad*4 + r
#pragma unroll
  for (int ti = 0; ti < 2; ti++) {
#pragma unroll
    for (int tj = 0; tj < 4; tj++) {
      int m = tj * 16 + mrow;
#pragma unroll
      for (int r = 0; r < 4; r++) {
        int row = wr + ti * 16 + quad * 4 + r;
        int l = l0 + row;
        float ov = zs[row] * acc0[ti][tj][r] + zc[row] * acc1[ti][tj][r];
        float xv = b2f(xT[((size_t)b * L_SEQ + l) * EDIM + hd * DHEAD + m]);
        attn[((size_t)l * BATCH + b) * EDIM + hd * DHEAD + m] = f2b(xv + ov);
      }
    }
  }
}

// ---------------------------------------------------------------------------
extern "C" void kernel_launch(void* const* d_in, const int* in_sizes, int n_in,
                              void* d_out, int out_size, void* d_ws, size_t ws_size,
                              hipStream_t stream) {
  const float* query = (const float*)d_in[0];
  const float* Wq = (const float*)d_in[1];
  const float* bq = (const float*)d_in[2];
  const float* Wk = (const float*)d_in[3];
  const float* bk = (const float*)d_in[4];
  const float* Wv = (const float*)d_in[5];
  const float* bv = (const float*)d_in[6];
  const float* Wo = (const float*)d_in[7];
  const float* bo = (const float*)d_in[8];
  float* out = (float*)d_out;  // fp32 output, 18432*768 elements

  // xT (bf16, 28.3 MB) staged inside d_out (56.6 MB fp32); last read by
  // attn_mfma, which completes before the final GEMM overwrites d_out.
  unsigned short* xT = (unsigned short*)d_out;

  char* ws = (char*)d_ws;
  const size_t SZ = (size_t)MROWS * EDIM * 2;  // 28,311,552
  unsigned short* qbuf = (unsigned short*)(ws);
  unsigned short* kbuf = (unsigned short*)(ws + SZ);
  unsigned short* vbuf = (unsigned short*)(ws + 2 * SZ);
  unsigned short* attn = kbuf;  // kbuf dead after kv_reduce
  float* kv   = (float*)(ws + 3 * SZ);                    // 3,145,728 B
  float* ksum = (float*)(ws + 3 * SZ + 3145728);          // 49,152 B
  unsigned short* wbf = (unsigned short*)(ws + 3 * SZ + 3145728 + 49152);
  // total ws: 92,848,128 B

  conv_w<<<dim3(576, 4), 256, 0, stream>>>(Wq, Wk, Wv, Wo, wbf);

  transpose_q<<<dim3(12, 36, 8), 256, 0, stream>>>(query, xT);

  gemm_bt<0><<<dim3(MROWS / 128, EDIM / 128, 3), 256, 0, stream>>>(
      xT, wbf, bq, bk, bv, qbuf, kbuf, vbuf, nullptr);

  hipMemsetAsync(ws + 3 * SZ, 0, 3145728 + 49152, stream);

  kv_reduce<<<dim3(96, 8), 256, 0, stream>>>(kbuf, vbuf, kv, ksum);

  attn_mfma<<<dim3(L_SEQ / 128, 96), 256, 0, stream>>>(qbuf, kv, ksum, xT, attn);

  gemm_bt<1><<<dim3(MROWS / 128, EDIM / 128, 1), 256, 0, stream>>>(
      attn, wbf + 3 * (size_t)EDIM * EDIM, bo, nullptr, nullptr,
      nullptr, nullptr, nullptr, out);
}

// Round 7
// 329.126 us; speedup vs baseline: 2.0735x; 1.1761x over previous
//
#include <hip/hip_runtime.h>

// CosformerAttention on MI355X (gfx950). Inputs fp32, OUTPUT fp32.
// B=8, E=768, L=48*48=2304, heads=12, d=64, n=B*h=96, M=L*B=18432.
//
// Round-7: kv_reduce (111 us, MfmaUtil 0, VALU-bound) rewritten as MFMA:
// kv = k_^T @ v per head via 16x16x32 bf16 MFMA with LDS-transposed staging
// (sin/cos fused), ksum via a ones-column B-tile. Rest unchanged from r6.

#define L_SEQ 2304
#define BATCH 8
#define EDIM 768
#define NHEAD 12
#define DHEAD 64
#define MROWS (L_SEQ * BATCH)  // 18432

typedef __attribute__((ext_vector_type(8))) short bf16x8_t;   // 8 bf16 = 4 VGPRs
typedef __attribute__((ext_vector_type(4))) float f32x4_t;

__device__ __forceinline__ float b2f(unsigned short u) {
  union { unsigned int i; float f; } x; x.i = ((unsigned int)u) << 16; return x.f;
}
__device__ __forceinline__ unsigned short f2b(float f) {
  union { float f; unsigned int i; } x; x.f = f;
  unsigned int r = x.i + 0x7FFFu + ((x.i >> 16) & 1u);  // RNE
  return (unsigned short)(r >> 16);
}

// async 16B global->LDS (gfx950; wave-uniform base + lane*16 dest contract)
#define GLOAD_LDS16(g, l)                                                     \
  __builtin_amdgcn_global_load_lds(                                           \
      (const __attribute__((address_space(1))) unsigned int*)(g),             \
      (__attribute__((address_space(3))) unsigned int*)(l), 16, 0, 0)

// ---------------------------------------------------------------------------
// Kernel 0: convert 4 fp32 weight matrices (768x768) to bf16.
__global__ __launch_bounds__(256) void conv_w(
    const float* __restrict__ W0, const float* __restrict__ W1,
    const float* __restrict__ W2, const float* __restrict__ W3,
    unsigned short* __restrict__ dst) {
  const float* W = (blockIdx.y == 0) ? W0 : (blockIdx.y == 1) ? W1
                 : (blockIdx.y == 2) ? W2 : W3;
  unsigned short* d = dst + (size_t)blockIdx.y * EDIM * EDIM;
  int idx = blockIdx.x * 256 + threadIdx.x;  // [0, 147456)
  float4 v = *(const float4*)(W + (size_t)idx * 4);
  ushort4 o;
  o.x = f2b(v.x); o.y = f2b(v.y); o.z = f2b(v.z); o.w = f2b(v.w);
  *(ushort4*)(d + (size_t)idx * 4) = o;
}

// ---------------------------------------------------------------------------
// Kernel 1: transpose query (B, E, L) fp32 -> xT (B*L, E) bf16.
__global__ __launch_bounds__(256) void transpose_q(
    const float* __restrict__ q, unsigned short* __restrict__ xT) {
  __shared__ float tile[64][65];
  int b = blockIdx.z;
  int e0 = blockIdx.x * 64;
  int l0 = blockIdx.y * 64;
  int t = threadIdx.x;
  int li = t & 63, er = t >> 6;
#pragma unroll
  for (int p = 0; p < 16; p++) {
    int eo = er + p * 4;
    tile[eo][li] = q[((size_t)b * EDIM + (e0 + eo)) * L_SEQ + (l0 + li)];
  }
  __syncthreads();
  int ei = t & 63, lr = t >> 6;
#pragma unroll
  for (int p = 0; p < 16; p++) {
    int lo = lr + p * 4;
    xT[((size_t)b * L_SEQ + (l0 + lo)) * EDIM + (e0 + ei)] = f2b(tile[ei][lo]);
  }
}

// ---------------------------------------------------------------------------
// Kernel 2/5: C = A @ W^T (+bias, opt relu). 128x128 tile, BK=32, 4 waves,
// 4x4 MFMA (16x16x32 bf16) acc/wave. Staging via global_load_lds width=16.
template <int MODE>
__global__ __launch_bounds__(256) void gemm_bt(
    const unsigned short* __restrict__ A,
    const unsigned short* __restrict__ Wall,
    const float* __restrict__ bias0, const float* __restrict__ bias1,
    const float* __restrict__ bias2,
    unsigned short* __restrict__ dst0, unsigned short* __restrict__ dst1,
    unsigned short* __restrict__ dst2,
    float* __restrict__ dstf) {
  constexpr int BM = 128, BN = 128, BK = 32, K = EDIM;
  __shared__ __align__(16) unsigned short As[BM * BK];
  __shared__ __align__(16) unsigned short Bs[BN * BK];

  const unsigned short* W;
  const float* bias;
  unsigned short* dst;
  bool do_relu;
  if (MODE == 0) {
    int z = blockIdx.z;
    W    = Wall + (size_t)z * EDIM * EDIM;
    bias = (z == 0) ? bias0 : (z == 1) ? bias1 : bias2;
    dst  = (z == 0) ? dst0 : (z == 1) ? dst1 : dst2;
    do_relu = (z < 2);
  } else {
    W = Wall; bias = bias0; dst = dst0; do_relu = false;
  }

  int t = threadIdx.x;
  int lane = t & 63;
  int wave = t >> 6;
  int wr = (wave & 1) * 64;
  int wc = (wave >> 1) * 64;
  int row0 = blockIdx.x * BM;
  int col0 = blockIdx.y * BN;
  int mrow = lane & 15, quad = lane >> 4;

  f32x4_t acc[4][4] = {};

  for (int k0 = 0; k0 < K; k0 += BK) {
#pragma unroll
    for (int i = 0; i < 2; i++) {
      int c = t + i * 256;
      int r = c >> 2;
      int kk = (c & 3) * 8;
      GLOAD_LDS16(A + (size_t)(row0 + r) * K + (k0 + kk), As + (size_t)c * 8);
      GLOAD_LDS16(W + (size_t)(col0 + r) * K + (k0 + kk), Bs + (size_t)c * 8);
    }
    __syncthreads();
    bf16x8_t af[4], bfr[4];
#pragma unroll
    for (int i = 0; i < 4; i++) {
      af[i]  = *(const bf16x8_t*)(As + (wr + i * 16 + mrow) * BK + quad * 8);
      bfr[i] = *(const bf16x8_t*)(Bs + (wc + i * 16 + mrow) * BK + quad * 8);
    }
#pragma unroll
    for (int ti = 0; ti < 4; ti++)
#pragma unroll
      for (int tj = 0; tj < 4; tj++)
        acc[ti][tj] = __builtin_amdgcn_mfma_f32_16x16x32_bf16(af[ti], bfr[tj], acc[ti][tj], 0, 0, 0);
    __syncthreads();
  }

  int bb = row0 / L_SEQ;
#pragma unroll
  for (int ti = 0; ti < 4; ti++) {
#pragma unroll
    for (int tj = 0; tj < 4; tj++) {
      int gc = col0 + wc + tj * 16 + (lane & 15);
      float bv = bias[gc];
#pragma unroll
      for (int r = 0; r < 4; r++) {
        int gr = row0 + wr + ti * 16 + quad * 4 + r;
        float v = acc[ti][tj][r] + bv;
        if (MODE == 0) {
          if (do_relu) v = fmaxf(v, 0.0f);
          int ll = gr - bb * L_SEQ;
          int n = bb * NHEAD + (gc >> 6);
          dst[((size_t)n * L_SEQ + ll) * DHEAD + (gc & 63)] = f2b(v);
        } else {
          dstf[(size_t)gr * EDIM + gc] = v;  // FP32 output
        }
      }
    }
  }
}

// ---------------------------------------------------------------------------
// Kernel 3 (MFMA): kv[n][j][m] = sum_l k_[l][j]*v[l][m], ksum[n][j] = sum_l k_.
// Per block (head n, 288-l chunk): 9 slices of 32 l. Stage ksT[j][l] (sin/cos
// fused, j in [0,128)) and vsT[m][l] (m in [0,64); rows 64..79 = ones-tile for
// ksum) transposed in LDS, stride 40 bf16 (16B-aligned rows). 4 waves; wave w
// owns j-tiles {2w,2w+1} x 5 n-tiles => 10 MFMA/slice. fp32 atomicAdd out.
__global__ __launch_bounds__(256) void kv_mfma(
    const unsigned short* __restrict__ kbuf, const unsigned short* __restrict__ vbuf,
    float* __restrict__ kv, float* __restrict__ ksum) {
  constexpr int ST = 40;  // LDS row stride (bf16)
  __shared__ __align__(16) unsigned short ksT[128 * ST];
  __shared__ __align__(16) unsigned short vsT[80 * ST];
  int n = blockIdx.x;
  int lbase = blockIdx.y * 288;
  int t = threadIdx.x;
  int lane = t & 63, wave = t >> 6;
  int mrow = lane & 15, quad = lane >> 4;

  // init ones-tile rows 64..79 of vsT (constant across slices)
  for (int i = t; i < 16 * ST; i += 256) {
    int row = i / ST, col = i % ST;
    vsT[(64 + row) * ST + col] = (row == 0 && col < 32) ? (unsigned short)0x3F80 : 0;
  }

  int lrd = t >> 3;   // l within slice, 0..31
  int oct = t & 7;    // d-octet
  const unsigned short* kbase = kbuf + (size_t)n * L_SEQ * DHEAD + oct * 8;
  const unsigned short* vbase = vbuf + (size_t)n * L_SEQ * DHEAD + oct * 8;

  f32x4_t acc[2][5] = {};

  for (int s = 0; s < 9; s++) {
    int l = lbase + s * 32 + lrd;
    float sv, cv;
    sincosf(1.5707963267948966f * (float)(l + 1) / 2304.0f, &sv, &cv);
    union { uint4 q; unsigned short u[8]; } kq, vq;
    kq.q = *(const uint4*)(kbase + (size_t)l * DHEAD);
    vq.q = *(const uint4*)(vbase + (size_t)l * DHEAD);
    __syncthreads();  // previous slice's fragment reads done (also covers init)
#pragma unroll
    for (int e = 0; e < 8; e++) {
      int d = oct * 8 + e;
      float kval = b2f(kq.u[e]);
      ksT[d * ST + lrd] = f2b(kval * sv);
      ksT[(64 + d) * ST + lrd] = f2b(kval * cv);
      vsT[d * ST + lrd] = vq.u[e];
    }
    __syncthreads();
    bf16x8_t af[2];
#pragma unroll
    for (int ti = 0; ti < 2; ti++)
      af[ti] = *(const bf16x8_t*)(ksT + ((wave * 2 + ti) * 16 + mrow) * ST + quad * 8);
#pragma unroll
    for (int tj = 0; tj < 5; tj++) {
      bf16x8_t bfv = *(const bf16x8_t*)(vsT + (tj * 16 + mrow) * ST + quad * 8);
#pragma unroll
      for (int ti = 0; ti < 2; ti++)
        acc[ti][tj] = __builtin_amdgcn_mfma_f32_16x16x32_bf16(af[ti], bfv, acc[ti][tj], 0, 0, 0);
    }
  }

  // epilogue: D col = lane&15, row = quad*4 + r
#pragma unroll
  for (int ti = 0; ti < 2; ti++) {
#pragma unroll
    for (int r = 0; r < 4; r++) {
      int j = (wave * 2 + ti) * 16 + quad * 4 + r;
#pragma unroll
      for (int tj = 0; tj < 4; tj++) {
        int m = tj * 16 + mrow;
        atomicAdd(&kv[((size_t)n * 128 + j) * 64 + m], acc[ti][tj][r]);
      }
      if (mrow == 0) atomicAdd(&ksum[n * 128 + j], acc[ti][4][r]);
    }
  }
}

// ---------------------------------------------------------------------------
// Kernel 4 (MFMA): C0 = q@kv0, C1 = q@kv1; out = zs*C0 + zc*C1; fused
// residual + relayout. grid (18, 96), block 256.
__global__ __launch_bounds__(256) void attn_mfma(
    const unsigned short* __restrict__ qbuf, const float* __restrict__ kv,
    const float* __restrict__ ksum, const unsigned short* __restrict__ xT,
    unsigned short* __restrict__ attn) {
  __shared__ __align__(16) unsigned short As[128 * 72];
  __shared__ __align__(16) unsigned short Bs[64 * 136];
  __shared__ float ks_l[128];
  __shared__ float zs[128], zc[128];
  int l0 = blockIdx.x * 128;
  int n = blockIdx.y;
  int t = threadIdx.x;
  int lane = t & 63, wave = t >> 6;
  int mrow = lane & 15, quad = lane >> 4;
  int b = n / NHEAD, hd = n % NHEAD;

  {
    int row = t >> 1, off = (t & 1) * 32;
    const unsigned short* src = qbuf + ((size_t)n * L_SEQ + l0 + row) * DHEAD + off;
    unsigned short* d = As + row * 72 + off;
#pragma unroll
    for (int c = 0; c < 4; c++)
      *(uint4*)(d + c * 8) = *(const uint4*)(src + c * 8);
  }
  {
    int j = t >> 1, mh = (t & 1) * 32;
    const float* src = kv + ((size_t)n * 128 + j) * 64 + mh;
#pragma unroll
    for (int mm = 0; mm < 32; mm++)
      Bs[(mh + mm) * 136 + j] = f2b(src[mm]);
  }
  if (t < 128) ks_l[t] = ksum[n * 128 + t];
  __syncthreads();

  if (t < 128) {
    float d0 = 0.f, d1 = 0.f;
    const unsigned short* arow = As + t * 72;
#pragma unroll
    for (int j = 0; j < 8; j++) {
      bf16x8_t v = *(const bf16x8_t*)(arow + j * 8);
#pragma unroll
      for (int e = 0; e < 8; e++) {
        float qv = b2f((unsigned short)v[e]);
        d0 += qv * ks_l[j * 8 + e];
        d1 += qv * ks_l[64 + j * 8 + e];
      }
    }
    float sv, cv;
    sincosf(1.5707963267948966f * (float)(l0 + t + 1) / 2304.0f, &sv, &cv);
    float z = 1.0f / fmaxf(sv * d0 + cv * d1, 1e-6f);
    zs[t] = z * sv;
    zc[t] = z * cv;
  }
  __syncthreads();

  int wr = wave * 32;
  f32x4_t acc0[2][4] = {}, acc1[2][4] = {};
#pragma unroll
  for (int ks = 0; ks < 2; ks++) {
    bf16x8_t af[2];
#pragma unroll
    for (int ti = 0; ti < 2; ti++)
      af[ti] = *(const bf16x8_t*)(As + (wr + ti * 16 + mrow) * 72 + ks * 32 + quad * 8);
#pragma unroll
    for (int tj = 0; tj < 4; tj++) {
      bf16x8_t b0 = *(const bf16x8_t*)(Bs + (tj * 16 + mrow) * 136 + ks * 32 + quad * 8);
      bf16x8_t b1 = *(const bf16x8_t*)(Bs + (tj * 16 + mrow) * 136 + 64 + ks * 32 + quad * 8);
#pragma unroll
      for (int ti = 0; ti < 2; ti++) {
        acc0[ti][tj] = __builtin_amdgcn_mfma_f32_16x16x32_bf16(af[ti], b0, acc0[ti][tj], 0, 0, 0);
        acc1[ti][tj] = __builtin_amdgcn_mfma_f32_16x16x32_bf16(af[ti], b1, acc1[ti][tj], 0, 0, 0);
      }
    }
  }

#pragma unroll
  for (int ti = 0; ti < 2; ti++) {
#pragma unroll
    for (int tj = 0; tj < 4; tj++) {
      int m = tj * 16 + mrow;
#pragma unroll
      for (int r = 0; r < 4; r++) {
        int row = wr + ti * 16 + quad * 4 + r;
        int l = l0 + row;
        float ov = zs[row] * acc0[ti][tj][r] + zc[row] * acc1[ti][tj][r];
        float xv = b2f(xT[((size_t)b * L_SEQ + l) * EDIM + hd * DHEAD + m]);
        attn[((size_t)l * BATCH + b) * EDIM + hd * DHEAD + m] = f2b(xv + ov);
      }
    }
  }
}

// ---------------------------------------------------------------------------
extern "C" void kernel_launch(void* const* d_in, const int* in_sizes, int n_in,
                              void* d_out, int out_size, void* d_ws, size_t ws_size,
                              hipStream_t stream) {
  const float* query = (const float*)d_in[0];
  const float* Wq = (const float*)d_in[1];
  const float* bq = (const float*)d_in[2];
  const float* Wk = (const float*)d_in[3];
  const float* bk = (const float*)d_in[4];
  const float* Wv = (const float*)d_in[5];
  const float* bv = (const float*)d_in[6];
  const float* Wo = (const float*)d_in[7];
  const float* bo = (const float*)d_in[8];
  float* out = (float*)d_out;  // fp32 output

  unsigned short* xT = (unsigned short*)d_out;  // bf16 staging inside d_out

  char* ws = (char*)d_ws;
  const size_t SZ = (size_t)MROWS * EDIM * 2;  // 28,311,552
  unsigned short* qbuf = (unsigned short*)(ws);
  unsigned short* kbuf = (unsigned short*)(ws + SZ);
  unsigned short* vbuf = (unsigned short*)(ws + 2 * SZ);
  unsigned short* attn = kbuf;  // kbuf dead after kv_mfma
  float* kv   = (float*)(ws + 3 * SZ);                    // 3,145,728 B
  float* ksum = (float*)(ws + 3 * SZ + 3145728);          // 49,152 B
  unsigned short* wbf = (unsigned short*)(ws + 3 * SZ + 3145728 + 49152);
  // total ws: 92,848,128 B

  conv_w<<<dim3(576, 4), 256, 0, stream>>>(Wq, Wk, Wv, Wo, wbf);

  transpose_q<<<dim3(12, 36, 8), 256, 0, stream>>>(query, xT);

  gemm_bt<0><<<dim3(MROWS / 128, EDIM / 128, 3), 256, 0, stream>>>(
      xT, wbf, bq, bk, bv, qbuf, kbuf, vbuf, nullptr);

  hipMemsetAsync(ws + 3 * SZ, 0, 3145728 + 49152, stream);

  kv_mfma<<<dim3(96, 8), 256, 0, stream>>>(kbuf, vbuf, kv, ksum);

  attn_mfma<<<dim3(L_SEQ / 128, 96), 256, 0, stream>>>(qbuf, kv, ksum, xT, attn);

  gemm_bt<1><<<dim3(MROWS / 128, EDIM / 128, 1), 256, 0, stream>>>(
      attn, wbf + 3 * (size_t)EDIM * EDIM, bo, nullptr, nullptr,
      nullptr, nullptr, nullptr, out);
}